// Round 6
// baseline (453.721 us; speedup 1.0000x reference)
//
#include <hip/hip_runtime.h>
#include <hip/hip_bf16.h>

// RGCN: 2-layer relational GCN + L2 normalize.
// R5: aggregate-then-transform BOTH layers (gathers read 25.6MB bf16 feature
//     buffers, not 77MB transformed buffers); fused sort+gather k_agg @512thr;
//     K=384 MFMA GEMMs; L2-norm fused into GEMM2 epilogue; 512-key buckets.

typedef unsigned int uint;
typedef unsigned short ushort;
typedef __attribute__((ext_vector_type(8))) short short8;
typedef __attribute__((ext_vector_type(16))) float floatx16;

#define IN_CH  128
#define OUT_CH 64
#define SCAN_CHUNK 2048
#define EPB 8192          // edges per partition block
#define KPB 512           // keys per bucket (256 nodes x 2 rels)
#define MAXBK 400         // bucket counters in k_count/k_part (NBK=391)
#define SRCCAP 5120       // LDS edge capacity per bucket (mean 4096, +5sigma<5120)

__device__ __forceinline__ ushort f2bf(float f) {
    uint u = __float_as_uint(f);
    u += 0x7FFF + ((u >> 16) & 1);
    return (ushort)(u >> 16);
}
__device__ __forceinline__ float bflo(uint u) { return __uint_as_float(u << 16); }
__device__ __forceinline__ float bfhi(uint u) { return __uint_as_float(u & 0xFFFF0000u); }

// ---------------- radix partition: key = 2*dst + et, bucket = key>>9 -------

__global__ void k_count(const int* __restrict__ dst, const int* __restrict__ et,
                        int* __restrict__ cntblk, int E, int NBK, int NBLK) {
    __shared__ int cnt[MAXBK];
    int tid = threadIdx.x, blk = blockIdx.x;
    for (int b = tid; b < NBK; b += 256) cnt[b] = 0;
    __syncthreads();
    int base = blk * EPB;
#pragma unroll 4
    for (int i = 0; i < EPB / 256; i++) {
        int e = base + i * 256 + tid;
        if (e < E) {
            int key = 2 * dst[e] + et[e];
            atomicAdd(&cnt[key >> 9], 1);
        }
    }
    __syncthreads();
    for (int b = tid; b < NBK; b += 256) cntblk[b * NBLK + blk] = cnt[b];
}

__global__ void k_scan_a(const int* __restrict__ deg, int* __restrict__ offs,
                         int* __restrict__ bsums, int n) {
    __shared__ int sdata[256];
    int b = blockIdx.x, t = threadIdx.x;
    int base = b * SCAN_CHUNK + t * 8;
    int v[8];
    int sum = 0;
#pragma unroll
    for (int i = 0; i < 8; i++) {
        int idx = base + i;
        int x = (idx < n) ? deg[idx] : 0;
        v[i] = sum;
        sum += x;
    }
    sdata[t] = sum;
    __syncthreads();
    for (int ofs = 1; ofs < 256; ofs <<= 1) {
        int val = sdata[t];
        int add = (t >= ofs) ? sdata[t - ofs] : 0;
        __syncthreads();
        sdata[t] = val + add;
        __syncthreads();
    }
    int texcl = (t == 0) ? 0 : sdata[t - 1];
    if (t == 255) bsums[b] = sdata[255];
#pragma unroll
    for (int i = 0; i < 8; i++) {
        int idx = base + i;
        if (idx < n) offs[idx] = texcl + v[i];
    }
}

__global__ void k_scan_b(int* __restrict__ bsums, int* __restrict__ offs, int nb, int n) {
    if (blockIdx.x == 0 && threadIdx.x == 0) {
        int run = 0;
        for (int b = 0; b < nb; b++) {
            int t = bsums[b];
            bsums[b] = run;
            run += t;
        }
        offs[n] = run;
    }
}

__global__ void k_scan_c(int* __restrict__ offs, const int* __restrict__ bsums, int n) {
    int i = blockIdx.x * blockDim.x + threadIdx.x;
    if (i < n) offs[i] += bsums[i / SCAN_CHUNK];
}

__global__ void k_part(const int* __restrict__ src, const int* __restrict__ dst,
                       const int* __restrict__ et, const int* __restrict__ basebb,
                       uint2* __restrict__ stage, int E, int NBK, int NBLK) {
    __shared__ int cnt[MAXBK];
    __shared__ int basel[MAXBK];
    int tid = threadIdx.x, blk = blockIdx.x;
    for (int b = tid; b < NBK; b += 256) {
        cnt[b] = 0;
        basel[b] = basebb[b * NBLK + blk];
    }
    __syncthreads();
    int base = blk * EPB;
#pragma unroll 4
    for (int i = 0; i < EPB / 256; i++) {
        int e = base + i * 256 + tid;
        if (e < E) {
            int s = src[e];
            int key = 2 * dst[e] + et[e];
            int bk = key >> 9;
            int r = atomicAdd(&cnt[bk], 1);
            stage[basel[bk] + r] = make_uint2((uint)s, (uint)key);
        }
    }
}

// ---------------- fp32 -> bf16 conversion of x ----------------

__global__ void k_cvt(const float* __restrict__ x, uint4* __restrict__ xb, int n8) {
    int i = blockIdx.x * 256 + threadIdx.x;
    if (i >= n8) return;
    const float4 f0 = ((const float4*)x)[(size_t)i * 2];
    const float4 f1 = ((const float4*)x)[(size_t)i * 2 + 1];
    uint4 o;
    o.x = (uint)f2bf(f0.x) | ((uint)f2bf(f0.y) << 16);
    o.y = (uint)f2bf(f0.z) | ((uint)f2bf(f0.w) << 16);
    o.z = (uint)f2bf(f1.x) | ((uint)f2bf(f1.y) << 16);
    o.w = (uint)f2bf(f1.z) | ((uint)f2bf(f1.w) << 16);
    xb[i] = o;
}

// ------------- weight pre-pack into MFMA-B fragment order (bf16) -----------
// 128-col tile (gemm1): chunk c = gn*512 + s*64 + h*32 + n -> B[s*16+h*8+j][gn*32+n].
// 64-col tile (gemm2): c = gn*512 + s*64 + h*32 + n, gn 0..1 (1024 chunks).
// Bpk1: 3 tiles (K-segs root/rel0/rel1) x 2048; Bpk2: 3 tiles x 1024.

__device__ __forceinline__ uint4 pack8(const ushort* o) {
    uint4 v;
    v.x = (uint)o[0] | ((uint)o[1] << 16);
    v.y = (uint)o[2] | ((uint)o[3] << 16);
    v.z = (uint)o[4] | ((uint)o[5] << 16);
    v.w = (uint)o[6] | ((uint)o[7] << 16);
    return v;
}

__global__ void k_prep(const float* __restrict__ W1root, const float* __restrict__ W1rel,
                       const float* __restrict__ W2root, const float* __restrict__ W2rel,
                       uint4* __restrict__ Bpk1, uint4* __restrict__ Bpk2) {
    int idx = blockIdx.x * 256 + threadIdx.x;
    if (idx >= 9216) return;
    ushort o[8];
    if (idx < 6144) {
        int id = idx;
        int ct = id >> 11;                 // K-segment: 0 root, 1 rel0, 2 rel1
        int c = id & 2047;
        int gn = c >> 9, s = (c >> 6) & 7, h = (c >> 5) & 1, n = c & 31;
        int k0 = s * 16 + h * 8;
        int col = gn * 32 + n;
        const float* W = (ct == 0) ? W1root : (W1rel + (size_t)(ct - 1) * 16384);
#pragma unroll
        for (int j = 0; j < 8; j++) o[j] = f2bf(W[(k0 + j) * 128 + col]);
        Bpk1[id] = pack8(o);
    } else {
        int id = idx - 6144;
        int ct = id >> 10;
        int c = id & 1023;
        int gn = c >> 9, s = (c >> 6) & 7, h = (c >> 5) & 1, n = c & 31;
        int k0 = s * 16 + h * 8;
        int col = gn * 32 + n;
        const float* W = (ct == 0) ? W2root : (W2rel + (size_t)(ct - 1) * 8192);
#pragma unroll
        for (int j = 0; j < 8; j++) o[j] = f2bf(W[(k0 + j) * 64 + col]);
        Bpk2[id] = pack8(o);
    }
}

// ------- fused: bucket fine-sort (LDS) + gather-mean of features -> S ------
// One block (512 thr, 8 waves) per 512-key bucket (256 nodes).
// doSort=1: sort from stage, emit esrc/offs. doSort=0: reload esrc/offs.
// Gather: feat bf16 rows [.. x 128ch]; per (node,rel): mean -> S[n][r*128..].

__global__ __launch_bounds__(512)
void k_agg(const uint2* __restrict__ stage, const int* __restrict__ basebb,
           const uint* __restrict__ feat, ushort* __restrict__ S,
           int* __restrict__ esrc, int* __restrict__ offs,
           int E, int N, int NBK, int NBLK, int doSort) {
    __shared__ int srcs[SRCCAP];
    __shared__ int kcnt[KPB];
    __shared__ int kends[KPB];
    __shared__ int stmp[KPB];
    int tid = threadIdx.x, b = blockIdx.x;
    int start = basebb[b * NBLK];
    int bend = (b == NBK - 1) ? E : basebb[(b + 1) * NBLK];
    int size = bend - start;

    if (doSort) {
        kcnt[tid] = 0;
        __syncthreads();
        for (int i = tid; i < size; i += 512) {
            uint2 p = stage[start + i];
            atomicAdd(&kcnt[p.y & (KPB - 1)], 1);
        }
        __syncthreads();
        int cnt = kcnt[tid];
        stmp[tid] = cnt;
        __syncthreads();
        for (int ofs = 1; ofs < KPB; ofs <<= 1) {
            int v = stmp[tid];
            if (tid >= ofs) v += stmp[tid - ofs];
            __syncthreads();
            stmp[tid] = v;
            __syncthreads();
        }
        int incl = stmp[tid];
        kends[tid] = incl;
        offs[b * KPB + tid] = start + incl;
        kcnt[tid] = incl - cnt;            // cursor = exclusive start
        __syncthreads();
        for (int i = tid; i < size; i += 512) {
            uint2 p = stage[start + i];
            int r = atomicAdd(&kcnt[p.y & (KPB - 1)], 1);
            if (r < SRCCAP) srcs[r] = (int)p.x;
            esrc[start + r] = (int)p.x;
        }
    } else {
        kends[tid] = offs[b * KPB + tid] - start;
        for (int i = tid; i < size; i += 512)
            if (i < SRCCAP) srcs[i] = esrc[start + i];
    }
    __syncthreads();

    // gather phase: wave w handles nodes ni = w, w+8, ...
    int w = tid >> 6, lane = tid & 63;
    int sub = lane >> 5, cl = lane & 31;
    const uint2* F = (const uint2*)feat;      // row stride 32 uint2 (128ch bf16)
    for (int ni = w; ni < 256; ni += 8) {
        int n = (b << 8) + ni;
        if (n >= N) break;
#pragma unroll
        for (int r = 0; r < 2; r++) {
            int lk = 2 * ni + r;
            int lbeg = lk ? kends[lk - 1] : 0;
            int lend = kends[lk];
            float a0 = 0.f, a1 = 0.f, a2 = 0.f, a3 = 0.f;
            for (int eb = lbeg; eb < lend; eb += 4) {
                uint2 v[2];
#pragma unroll
                for (int j = 0; j < 2; j++) {
                    int ee = eb + 2 * j + sub;
                    int id = (ee < lend) ? srcs[ee < SRCCAP ? ee : 0] : N; // row N zeros
                    v[j] = F[(size_t)id * 32 + cl];
                }
#pragma unroll
                for (int j = 0; j < 2; j++) {
                    a0 += bflo(v[j].x); a1 += bfhi(v[j].x);
                    a2 += bflo(v[j].y); a3 += bfhi(v[j].y);
                }
            }
            a0 += __shfl_xor(a0, 32, 64);
            a1 += __shfl_xor(a1, 32, 64);
            a2 += __shfl_xor(a2, 32, 64);
            a3 += __shfl_xor(a3, 32, 64);
            if (sub == 0) {
                float inv = (lend > lbeg) ? 1.0f / (float)(lend - lbeg) : 0.f;
                uint2 o;
                o.x = (uint)f2bf(a0 * inv) | ((uint)f2bf(a1 * inv) << 16);
                o.y = (uint)f2bf(a2 * inv) | ((uint)f2bf(a3 * inv) << 16);
                ((uint2*)(S + (size_t)n * 256 + r * 128))[cl] = o;
            }
        }
    }
}

// ------- GEMM1: h = relu([xb | S1] @ Bpk1 + b1), K=384, 128 cols, bf16 out --

__global__ __launch_bounds__(256)
void k_gemm1(const ushort* __restrict__ xb, const ushort* __restrict__ S1,
             const ushort* __restrict__ Bpk, const float* __restrict__ b1,
             ushort* __restrict__ h, int N) {
    __shared__ ushort SH[32768];          // A 32KB + B 32KB
    ushort* Alds = SH;
    ushort* Blds = SH + 16384;

    const int tid = threadIdx.x;
    const int lane = tid & 63;
    const int w = tid >> 6;
    const int wm = w >> 1, wn = w & 1;
    const int rowBase = blockIdx.x * 128;

    floatx16 acc[2][2] = {};

#pragma unroll
    for (int seg = 0; seg < 3; seg++) {
        const ushort* Ap = (seg == 0) ? xb : S1;
        const int stride = (seg == 0) ? 128 : 256;
        const int aoff = (seg == 2) ? 128 : 0;
        const uint4* Bsrc = (const uint4*)Bpk + seg * 2048;
#pragma unroll
        for (int i = 0; i < 8; i++) {
            int c = tid + i * 256;
            int m = c & 31, hh = (c >> 5) & 1, s = (c >> 6) & 7, g = c >> 9;
            int row = rowBase + g * 32 + m;
            if (row >= N) row = N - 1;
            int kc = s * 2 + hh;
            ((uint4*)Alds)[c] = *(const uint4*)(Ap + (size_t)row * stride + aoff + kc * 8);
            ((uint4*)Blds)[c] = Bsrc[c];
        }
        __syncthreads();
#pragma unroll
        for (int s = 0; s < 8; s++) {
            short8 a0 = *(const short8*)&Alds[(((wm * 2 + 0) * 8 + s) * 64 + lane) * 8];
            short8 a1 = *(const short8*)&Alds[(((wm * 2 + 1) * 8 + s) * 64 + lane) * 8];
            short8 b0 = *(const short8*)&Blds[(((wn * 2 + 0) * 8 + s) * 64 + lane) * 8];
            short8 b1f = *(const short8*)&Blds[(((wn * 2 + 1) * 8 + s) * 64 + lane) * 8];
            acc[0][0] = __builtin_amdgcn_mfma_f32_32x32x16_bf16(a0, b0, acc[0][0], 0, 0, 0);
            acc[0][1] = __builtin_amdgcn_mfma_f32_32x32x16_bf16(a0, b1f, acc[0][1], 0, 0, 0);
            acc[1][0] = __builtin_amdgcn_mfma_f32_32x32x16_bf16(a1, b0, acc[1][0], 0, 0, 0);
            acc[1][1] = __builtin_amdgcn_mfma_f32_32x32x16_bf16(a1, b1f, acc[1][1], 0, 0, 0);
        }
        __syncthreads();
    }

    // epilogue: +bias, relu, bf16 -> Clds[128][136], vectorized stores
    ushort* Clds = SH;
    const int qr = 4 * (lane >> 5);
    const int cl = lane & 31;
    float bb[2];
#pragma unroll
    for (int nt = 0; nt < 2; nt++) bb[nt] = b1[wn * 64 + nt * 32 + cl];
#pragma unroll
    for (int mt = 0; mt < 2; mt++)
#pragma unroll
        for (int nt = 0; nt < 2; nt++) {
#pragma unroll
            for (int reg = 0; reg < 16; reg++) {
                int rl = (reg & 3) + 8 * (reg >> 2) + qr;
                float v = fmaxf(acc[mt][nt][reg] + bb[nt], 0.f);
                Clds[(wm * 64 + mt * 32 + rl) * 136 + wn * 64 + nt * 32 + cl] = f2bf(v);
            }
        }
    __syncthreads();

    int r = tid >> 1, half = tid & 1;
    int grow = rowBase + r;
    if (grow < N) {
#pragma unroll
        for (int k = 0; k < 8; k++) {
            int c0 = half * 64 + k * 8;
            uint4 v = *(const uint4*)&Clds[r * 136 + c0];
            *(uint4*)(h + (size_t)grow * 128 + c0) = v;
        }
    }
}

// ------- GEMM2: out = l2norm([h | S2] @ Bpk2 + b2), K=384, 64 cols, fp32 ---
// 4 waves over 128 rows (32 each); each wave covers both 32-col blocks.

__global__ __launch_bounds__(256)
void k_gemm2(const ushort* __restrict__ hA, const ushort* __restrict__ S2,
             const ushort* __restrict__ Bpk, const float* __restrict__ b2,
             float* __restrict__ out, int N) {
    __shared__ ushort SH[24576];          // A 32KB + B 16KB; C fp32 reuses (34.8KB)
    ushort* Alds = SH;
    ushort* Blds = SH + 16384;

    const int tid = threadIdx.x;
    const int lane = tid & 63;
    const int wm = tid >> 6;              // 0..3 row-group
    const int rowBase = blockIdx.x * 128;

    floatx16 acc[2] = {};

#pragma unroll
    for (int seg = 0; seg < 3; seg++) {
        const ushort* Ap = (seg == 0) ? hA : S2;
        const int stride = (seg == 0) ? 128 : 256;
        const int aoff = (seg == 2) ? 128 : 0;
        const uint4* Bsrc = (const uint4*)Bpk + seg * 1024;
#pragma unroll
        for (int i = 0; i < 8; i++) {
            int c = tid + i * 256;
            int m = c & 31, hh = (c >> 5) & 1, s = (c >> 6) & 7, g = c >> 9;
            int row = rowBase + g * 32 + m;
            if (row >= N) row = N - 1;
            int kc = s * 2 + hh;
            ((uint4*)Alds)[c] = *(const uint4*)(Ap + (size_t)row * stride + aoff + kc * 8);
        }
#pragma unroll
        for (int i = 0; i < 4; i++) {
            int c = tid + i * 256;
            ((uint4*)Blds)[c] = Bsrc[c];
        }
        __syncthreads();
#pragma unroll
        for (int s = 0; s < 8; s++) {
            short8 a = *(const short8*)&Alds[((wm * 8 + s) * 64 + lane) * 8];
            short8 b0 = *(const short8*)&Blds[((0 * 8 + s) * 64 + lane) * 8];
            short8 b1f = *(const short8*)&Blds[((8 + s) * 64 + lane) * 8];
            acc[0] = __builtin_amdgcn_mfma_f32_32x32x16_bf16(a, b0, acc[0], 0, 0, 0);
            acc[1] = __builtin_amdgcn_mfma_f32_32x32x16_bf16(a, b1f, acc[1], 0, 0, 0);
        }
        __syncthreads();
    }

    // epilogue: +bias -> Clds fp32 [128][68], row L2-norm, fp32 stores
    float* Cl = (float*)SH;
    const int cl = lane & 31;
    const int qr = 4 * (lane >> 5);
#pragma unroll
    for (int blk = 0; blk < 2; blk++) {
        float bb = b2[blk * 32 + cl];
#pragma unroll
        for (int reg = 0; reg < 16; reg++) {
            int rl = (reg & 3) + 8 * (reg >> 2) + qr;
            Cl[(wm * 32 + rl) * 68 + blk * 32 + cl] = acc[blk][reg] + bb;
        }
    }
    __syncthreads();

    int r = tid >> 1, half = tid & 1;
    int grow = rowBase + r;
    float4 v[8];
    float sq = 0.f;
#pragma unroll
    for (int j = 0; j < 8; j++) {
        v[j] = *(const float4*)&Cl[r * 68 + half * 32 + j * 4];
        sq += v[j].x * v[j].x + v[j].y * v[j].y + v[j].z * v[j].z + v[j].w * v[j].w;
    }
    sq += __shfl_xor(sq, 1, 64);
    float rn = 1.0f / fmaxf(sqrtf(sq), 1e-12f);
    if (grow < N) {
#pragma unroll
        for (int j = 0; j < 8; j++) {
            float4 o = {v[j].x * rn, v[j].y * rn, v[j].z * rn, v[j].w * rn};
            *(float4*)(out + (size_t)grow * 64 + half * 32 + j * 4) = o;
        }
    }
}

// ---------------- launch ----------------

extern "C" void kernel_launch(void* const* d_in, const int* in_sizes, int n_in,
                              void* d_out, int out_size, void* d_ws, size_t ws_size,
                              hipStream_t stream) {
    const float* x      = (const float*)d_in[0];
    const int*   ei     = (const int*)d_in[1];
    const int*   etype  = (const int*)d_in[2];
    const float* W1rel  = (const float*)d_in[3];
    const float* W1root = (const float*)d_in[4];
    const float* b1     = (const float*)d_in[5];
    const float* W2rel  = (const float*)d_in[6];
    const float* W2root = (const float*)d_in[7];
    const float* b2     = (const float*)d_in[8];
    float* out = (float*)d_out;

    const int N = in_sizes[0] / IN_CH;   // 100000
    const int E = in_sizes[2];           // 1600000
    const int NKEY = 2 * N;
    const int NBK  = (NKEY + KPB - 1) / KPB;   // 391 buckets
    const int NBLK = (E + EPB - 1) / EPB;      // 196 partition blocks
    const int NSC  = NBK * NBLK;

    const int* src = ei;
    const int* dst = ei + E;

    char* base = (char*)d_ws;
    size_t off = 0;
    auto carve = [&](size_t bytes) -> void* {
        void* p = base + off;
        off = (off + bytes + 511) & ~(size_t)511;
        return p;
    };
    ushort* xb    = (ushort*)carve((size_t)(N + 1) * 128 * sizeof(ushort)); // +zero row
    ushort* hA    = (ushort*)carve((size_t)(N + 1) * 128 * sizeof(ushort)); // +zero row
    ushort* S1    = (ushort*)carve((size_t)N * 256 * sizeof(ushort));       // 51.2MB
    int*    esrc  = (int*)carve((size_t)E * sizeof(int));
    uint2*  stage = (uint2*)carve((size_t)E * sizeof(uint2));
    int*    offs  = (int*)carve((size_t)NBK * KPB * sizeof(int));
    int*    cntblk= (int*)carve((size_t)NSC * sizeof(int));
    int*    basebb= (int*)carve((size_t)(NSC + 1) * sizeof(int));
    int     NB    = (NSC + SCAN_CHUNK - 1) / SCAN_CHUNK;
    int*    bsums = (int*)carve((size_t)NB * sizeof(int));
    uint4*  Bpk1  = (uint4*)carve(6144 * sizeof(uint4));
    uint4*  Bpk2  = (uint4*)carve(3072 * sizeof(uint4));
    ushort* S2 = S1;    // S1 dead after gemm1
    (void)ws_size; (void)n_in; (void)out_size;

    // zero rows (id==N in gathers)
    hipMemsetAsync(xb + (size_t)N * 128, 0, 128 * sizeof(ushort), stream);
    hipMemsetAsync(hA + (size_t)N * 128, 0, 128 * sizeof(ushort), stream);

    // radix partition
    k_count<<<NBLK, 256, 0, stream>>>(dst, etype, cntblk, E, NBK, NBLK);
    k_scan_a<<<NB, 256, 0, stream>>>(cntblk, basebb, bsums, NSC);
    k_scan_b<<<1, 64, 0, stream>>>(bsums, basebb, NB, NSC);
    k_scan_c<<<(NSC + 255) / 256, 256, 0, stream>>>(basebb, bsums, NSC);
    k_part<<<NBLK, 256, 0, stream>>>(src, dst, etype, basebb, stage, E, NBK, NBLK);

    int n8 = N * 16;
    k_cvt<<<(n8 + 255) / 256, 256, 0, stream>>>(x, (uint4*)xb, n8);
    k_prep<<<36, 256, 0, stream>>>(W1root, W1rel, W2root, W2rel, Bpk1, Bpk2);

    int rowTiles = (N + 127) / 128;

    // Layer 1: S1 = seg-mean(xb), h = relu([xb|S1] @ W1 + b1)
    k_agg<<<NBK, 512, 0, stream>>>(stage, basebb, (const uint*)xb, S1,
                                   esrc, offs, E, N, NBK, NBLK, 1);
    k_gemm1<<<rowTiles, 256, 0, stream>>>(xb, S1, (const ushort*)Bpk1, b1, hA, N);

    // Layer 2: S2 = seg-mean(h), out = l2norm([h|S2] @ W2 + b2)
    k_agg<<<NBK, 512, 0, stream>>>(stage, basebb, (const uint*)hA, S2,
                                   esrc, offs, E, N, NBK, NBLK, 0);
    k_gemm2<<<rowTiles, 256, 0, stream>>>(hA, S2, (const ushort*)Bpk2, b2, out, N);
}